// Round 14
// baseline (222.250 us; speedup 1.0000x reference)
//
#include <hip/hip_runtime.h>

#define DEV __device__ __forceinline__

constexpr int B_  = 4;
constexpr int C_  = 256;
constexpr int C8_ = 32;
constexpr int N_  = 4096;   // 64*64
constexpr float LOG2E = 1.4426950408889634f;

using u16 = unsigned short;
using u32 = unsigned int;

typedef __attribute__((ext_vector_type(8))) short bf16x8;
typedef __attribute__((ext_vector_type(4))) float f32x4;

DEV float bf2f(u16 u) { return __uint_as_float(((u32)u) << 16); }
DEV u16   f2bf(float f) {
  u32 i = __float_as_uint(f);
  i += 0x7fffu + ((i >> 16) & 1u);   // round-to-nearest-even
  return (u16)(i >> 16);
}
// pack two floats to bf16x2 (RTZ) in ONE v_perm_b32
DEV u32 pack_rtz(float a, float b) {
  return __builtin_amdgcn_perm(__float_as_uint(b), __float_as_uint(a), 0x07060302);
}

// LDS-only barrier: cross-wave data is in LDS only -> skip the vmcnt(0) drain
DEV void lds_barrier() {
  asm volatile("s_waitcnt lgkmcnt(0)\n\ts_barrier" ::: "memory");
}

// ---------------------------------------------------------------------------
// prep: WEIGHTS ONLY (x-transpose fused into qkv_mfma, r9).
//   Wq*log2e, Wk -> hi/lo; Wv -> hi; Wo -> hi/lo.   grid 576.
// ---------------------------------------------------------------------------
__global__ __launch_bounds__(256) void prep(
    const float* __restrict__ Wq, const float* __restrict__ Wk,
    const float* __restrict__ Wv, const float* __restrict__ Wo,
    u16* __restrict__ WqH, u16* __restrict__ WqL,
    u16* __restrict__ WkH, u16* __restrict__ WkL,
    u16* __restrict__ WvH,
    u16* __restrict__ WoH, u16* __restrict__ WoL)
{
  const int i = blockIdx.x * 256 + threadIdx.x;
  if (i < 8192) {
    float v = Wq[i] * LOG2E;
    u16 h = f2bf(v); WqH[i] = h; WqL[i] = f2bf(v - bf2f(h));
  } else if (i < 16384) {
    int off = i - 8192;
    float v = Wk[off];
    u16 h = f2bf(v); WkH[off] = h; WkL[off] = f2bf(v - bf2f(h));
  } else if (i < 81920) {
    int off = i - 16384;
    WvH[off] = f2bf(Wv[off]);
  } else {
    int off = i - 81920;
    float v = Wo[off];
    u16 h = f2bf(v); WoH[off] = h; WoL[off] = f2bf(v - bf2f(h));
  }
}

// ---------------------------------------------------------------------------
// q/k/v projections + FUSED x-transpose.
// Round-14 (= r13 resubmit; container failed, no verdict): 16-PIXEL TILES
// (was 32) -> grid 1024 blocks, LDS 68->34 KB.
//   qkv was TLP-starved: 512 blocks = 2/CU AND 68KB LDS capped residency at
//   2.  Its K-loop is latency-bound (8 dependent L2 weight loads/iter) with
//   only 1-2 barriers TOTAL per block -> more resident blocks is pure
//   latency-hiding (the r4/r5 "more tiles" hazard doesn't apply here).
//   Per-pixel work identical; weight re-reads double but L2-resident.
// grid (N/16, B), block 256.
// ---------------------------------------------------------------------------
__global__ __launch_bounds__(256) void qkv_mfma(
    const float* __restrict__ x,
    const u16* __restrict__ WqH, const u16* __restrict__ WqL,
    const u16* __restrict__ WkH, const u16* __restrict__ WkL,
    const u16* __restrict__ WvH,
    const float* __restrict__ bq, const float* __restrict__ bk,
    const float* __restrict__ bv,
    u16* __restrict__ qt, u16* __restrict__ kt, u16* __restrict__ vb,
    u16* __restrict__ xTh)
{
  __shared__ float tf[16][261];
  __shared__ __align__(16) u16 xsh[16][270];
  __shared__ __align__(16) u16 xsl[16][270];

  const int tid = threadIdx.x;
  const int lane = tid & 63, w = tid >> 6, m = lane & 15, quad = lane >> 4;
  const int b = blockIdx.y, n0 = blockIdx.x * 16;

  // --- stage 1: x rows -> tf, float4 along n (4 lanes cover one 16-n row)
  {
    const int row = tid >> 2, seg = (tid & 3) * 4;   // row 0..63 (c), seg 0..12
    #pragma unroll
    for (int it = 0; it < 4; ++it) {
      int c = it * 64 + row;
      float4 v = *(const float4*)&x[((size_t)b * C_ + c) * N_ + n0 + seg];
      tf[seg + 0][c] = v.x;
      tf[seg + 1][c] = v.y;
      tf[seg + 2][c] = v.z;
      tf[seg + 3][c] = v.w;
    }
  }
  __syncthreads();

  // --- stage 2: convert to hi/lo bf16; write LDS tiles + xTh side-output
  {
    const int n = tid >> 4;                          // 0..15
    const int cb = (tid & 15) * 8;                   // c = cb + 128*it
    #pragma unroll
    for (int it = 0; it < 2; ++it) {
      int c = cb + it * 128;
      u32 ph[4], pl[4];
      #pragma unroll
      for (int j = 0; j < 4; ++j) {
        float v0 = tf[n][c + 2 * j], v1 = tf[n][c + 2 * j + 1];
        u16 h0 = f2bf(v0), h1 = f2bf(v1);
        ph[j] = (u32)h0 | ((u32)h1 << 16);
        pl[j] = (u32)f2bf(v0 - bf2f(h0)) | ((u32)f2bf(v1 - bf2f(h1)) << 16);
      }
      uint4 hv = make_uint4(ph[0], ph[1], ph[2], ph[3]);
      *(uint4*)&xsh[n][c] = hv;
      *(uint4*)&xsl[n][c] = make_uint4(pl[0], pl[1], pl[2], pl[3]);
      *(uint4*)&xTh[((size_t)b * N_ + n0 + n) * C_ + c] = hv;
    }
  }
  __syncthreads();

  const u16* qkH = (w < 2) ? (WqH + (size_t)(w * 16 + m) * C_)
                           : (WkH + (size_t)((w - 2) * 16 + m) * C_);
  const u16* qkL = (w < 2) ? (WqL + (size_t)(w * 16 + m) * C_)
                           : (WkL + (size_t)((w - 2) * 16 + m) * C_);

  f32x4 ov[4], oq;
  #pragma unroll
  for (int dt = 0; dt < 4; ++dt) ov[dt] = (f32x4){0.f, 0.f, 0.f, 0.f};
  oq = (f32x4){0.f, 0.f, 0.f, 0.f};

  for (int K = 0; K < 8; ++K) {
    const int ko = K * 32 + quad * 8;
    bf16x8 xh = *(const bf16x8*)&xsh[m][ko];
    bf16x8 xl = *(const bf16x8*)&xsl[m][ko];
    #pragma unroll
    for (int dt = 0; dt < 4; ++dt) {
      bf16x8 whi = *(const bf16x8*)(WvH + (size_t)(64 * w + dt * 16 + m) * C_ + ko);
      ov[dt] = __builtin_amdgcn_mfma_f32_16x16x32_bf16(whi, xh, ov[dt], 0, 0, 0);
    }
    {
      bf16x8 bhi = *(const bf16x8*)(qkH + ko);
      bf16x8 blo = *(const bf16x8*)(qkL + ko);
      oq = __builtin_amdgcn_mfma_f32_16x16x32_bf16(xh, bhi, oq, 0, 0, 0);
      oq = __builtin_amdgcn_mfma_f32_16x16x32_bf16(xl, bhi, oq, 0, 0, 0);
      oq = __builtin_amdgcn_mfma_f32_16x16x32_bf16(xh, blo, oq, 0, 0, 0);
    }
  }

  #pragma unroll
  for (int dt = 0; dt < 4; ++dt)
    #pragma unroll
    for (int r = 0; r < 4; ++r) {
      int oc = 64 * w + dt * 16 + quad * 4 + r;
      vb[((size_t)b * C_ + oc) * N_ + n0 + m] = f2bf(ov[dt][r] + bv[oc]);
    }
  {
    u16* qk_out = (w < 2) ? qt : kt;
    int dbase = (w & 1) * 16;
    float bias = (w < 2) ? bq[dbase + m] * LOG2E : bk[dbase + m];
    #pragma unroll
    for (int r = 0; r < 4; ++r)
      qk_out[((size_t)b * N_ + n0 + quad * 4 + r) * C8_ + dbase + m] =
          f2bf(oq[r] + bias);
  }
}

// ---------------------------------------------------------------------------
// MFMA flash attention, SPLIT-K=2, TJ=128, exp2 softmax, defer-max.
// (byte-identical to r9/r12: attn ~88us.  Scheduling grafts 0-for-3 here —
// serial schedule + 2-wave TLP is this structure's optimum.)
// grid (N/64, 2, B) linearized; block 256 (4 waves).
// ---------------------------------------------------------------------------
__global__ __launch_bounds__(256) void attn_mfma(
    const u16* __restrict__ qt, const u16* __restrict__ kt,
    const u16* __restrict__ vb,
    u16* __restrict__ Onorm, float* __restrict__ ml)
{
  __shared__ __align__(16) u16  ps[2][64][136];
  __shared__ __align__(16) float als[2][64];
  __shared__ float lfin[64];

  const int tid = threadIdx.x, lane = tid & 63, w = tid >> 6;
  const int m = lane & 15, quad = lane >> 4;

  const int lid = blockIdx.x + gridDim.x * (blockIdx.y + gridDim.y * blockIdx.z);
  const int grp = lid & 7, ksl = grp & 1, b = grp >> 1;
  const int i0 = (lid >> 3) * 64;

  const bf16x8 qfrag =
      *(const bf16x8*)(qt + ((size_t)b * N_ + i0 + w * 16 + m) * C8_ + quad * 8);
  const u16* kbase = kt + (size_t)b * N_ * C8_;
  const u16* vrow  = vb + ((size_t)b * C_ + w * 64 + m) * N_;

  f32x4 o[4][4];
  #pragma unroll
  for (int t = 0; t < 4; ++t)
    #pragma unroll
    for (int ct = 0; ct < 4; ++ct) o[t][ct] = (f32x4){0.f, 0.f, 0.f, 0.f};
  float m_r = -1e30f, l_r = 0.f;

  const int jbeg = ksl * 2048, jend = jbeg + 2048;
  int buf = 0;

  for (int j0 = jbeg; j0 < jend; j0 += 128, buf ^= 1) {
    // --- S, K in two register halves (peak 16 K-regs instead of 32)
    f32x4 s[8];
    bf16x8 kA[4];
    #pragma unroll
    for (int t = 0; t < 4; ++t)
      kA[t] = *(const bf16x8*)(kbase + (size_t)(j0 + t * 16 + m) * C8_ + quad * 8);
    #pragma unroll
    for (int t = 0; t < 4; ++t)
      s[t] = __builtin_amdgcn_mfma_f32_16x16x32_bf16(
          kA[t], qfrag, (f32x4){0.f, 0.f, 0.f, 0.f}, 0, 0, 0);
    // V first half (kk=0,1) issued here: consumed after the barrier
    bf16x8 vB[4][2];
    #pragma unroll
    for (int ct = 0; ct < 4; ++ct)
      #pragma unroll
      for (int kk = 0; kk < 2; ++kk)
        vB[ct][kk] = *(const bf16x8*)(vrow + (size_t)ct * 16 * N_ + j0 + kk * 32 + quad * 8);
    #pragma unroll
    for (int t = 0; t < 4; ++t)
      kA[t] = *(const bf16x8*)(kbase + (size_t)(j0 + (t + 4) * 16 + m) * C8_ + quad * 8);
    #pragma unroll
    for (int t = 0; t < 4; ++t)
      s[t + 4] = __builtin_amdgcn_mfma_f32_16x16x32_bf16(
          kA[t], qfrag, (f32x4){0.f, 0.f, 0.f, 0.f}, 0, 0, 0);

    // --- register online softmax, IN-PLACE on s (log2 domain)
    float mx = -1e30f;
    #pragma unroll
    for (int t = 0; t < 8; ++t)
      #pragma unroll
      for (int r = 0; r < 4; ++r) mx = fmaxf(mx, s[t][r]);
    mx = fmaxf(mx, __shfl_xor(mx, 16));
    mx = fmaxf(mx, __shfl_xor(mx, 32));
    // defer-max: keep stale max while tile max grows <= 8 (P <= 2^8, bf16-safe)
    float mn = (mx - m_r <= 8.f) ? m_r : mx;
    float al = exp2f(m_r - mn);          // == 1.0f exactly when deferred
    m_r = mn;
    float sm = 0.f;
    #pragma unroll
    for (int t = 0; t < 8; ++t)
      #pragma unroll
      for (int r = 0; r < 4; ++r) {
        s[t][r] = exp2f(s[t][r] - mn);
        sm += s[t][r];
      }
    sm += __shfl_xor(sm, 16);
    sm += __shfl_xor(sm, 32);
    l_r = l_r * al + sm;

    #pragma unroll
    for (int t = 0; t < 8; ++t)
      *(uint2*)&ps[buf][w * 16 + m][t * 16 + quad * 4] =
          make_uint2(pack_rtz(s[t][0], s[t][1]), pack_rtz(s[t][2], s[t][3]));
    if (quad == 0) als[buf][w * 16 + m] = al;

    lds_barrier();   // LDS visibility only; V loads stay outstanding

    // --- rescale O (skipped when every row's al == 1, the common deferred case)
    #pragma unroll
    for (int t = 0; t < 4; ++t) {
      float4 alv = *(const float4*)&als[buf][t * 16 + quad * 4];
      int need = (alv.x < 1.f) | (alv.y < 1.f) | (alv.z < 1.f) | (alv.w < 1.f);
      if (__any(need)) {
        #pragma unroll
        for (int ct = 0; ct < 4; ++ct) {
          o[t][ct][0] *= alv.x; o[t][ct][1] *= alv.y;
          o[t][ct][2] *= alv.z; o[t][ct][3] *= alv.w;
        }
      }
    }

    // --- PV kk = 0,1
    #pragma unroll
    for (int kk = 0; kk < 2; ++kk)
      #pragma unroll
      for (int t = 0; t < 4; ++t) {
        bf16x8 pf = *(const bf16x8*)&ps[buf][t * 16 + m][kk * 32 + quad * 8];
        #pragma unroll
        for (int ct = 0; ct < 4; ++ct)
          o[t][ct] = __builtin_amdgcn_mfma_f32_16x16x32_bf16(pf, vB[ct][kk], o[t][ct], 0, 0, 0);
      }

    // pin: reload of V (kk=2,3) must NOT be hoisted above PV kk=0,1
    __builtin_amdgcn_sched_barrier(0);

    #pragma unroll
    for (int ct = 0; ct < 4; ++ct)
      #pragma unroll
      for (int kk = 0; kk < 2; ++kk)
        vB[ct][kk] = *(const bf16x8*)(vrow + (size_t)ct * 16 * N_ + j0 + (kk + 2) * 32 + quad * 8);

    // --- PV kk = 2,3
    #pragma unroll
    for (int kk = 0; kk < 2; ++kk)
      #pragma unroll
      for (int t = 0; t < 4; ++t) {
        bf16x8 pf = *(const bf16x8*)&ps[buf][t * 16 + m][(kk + 2) * 32 + quad * 8];
        #pragma unroll
        for (int ct = 0; ct < 4; ++ct)
          o[t][ct] = __builtin_amdgcn_mfma_f32_16x16x32_bf16(pf, vB[ct][kk], o[t][ct], 0, 0, 0);
      }
  }

  // share 1/l across waves (O rows span all 64 block queries)
  if (quad == 0) lfin[w * 16 + m] = 1.f / l_r;
  lds_barrier();

  u16* Ob = Onorm + (((size_t)ksl * B_ + b) * N_ + i0) * C_ + w * 64;
  #pragma unroll
  for (int t = 0; t < 4; ++t) {
    float4 lv = *(const float4*)&lfin[t * 16 + quad * 4];
    float linv[4] = {lv.x, lv.y, lv.z, lv.w};
    #pragma unroll
    for (int ct = 0; ct < 4; ++ct)
      #pragma unroll
      for (int r = 0; r < 4; ++r)
        Ob[(size_t)(t * 16 + quad * 4 + r) * C_ + ct * 16 + m] = f2bf(o[t][ct][r] * linv[r]);
  }

  if (quad == 0) {
    size_t mli = ((size_t)ksl * B_ + b) * N_ + i0 + w * 16 + m;
    ml[mli] = m_r;                                   // m_s at s*BN
    ml[(size_t)2 * B_ * N_ + mli] = l_r;             // l_s at (2+s)*BN
  }
}

// ---------------------------------------------------------------------------
// Fused split-K combine (2 splits) + residual + final 1x1 conv.
// Round-14 (= r13 resubmit): 16-PIXEL TILES (was 32) -> grid 1024 blocks
// (4/CU), LDS 8.7 KB.  Same TLP-starvation fix as qkv: latency-bound
// K-loop, 1 barrier/block.
// grid (N/16, B), block 256.
// ---------------------------------------------------------------------------
__global__ __launch_bounds__(256) void out_mfma(
    const u16* __restrict__ Onorm, const float* __restrict__ ml,
    const u16* __restrict__ xTh,
    const u16* __restrict__ WoH, const u16* __restrict__ WoL,
    const float* __restrict__ bo, float* __restrict__ out)
{
  __shared__ __align__(16) u16 hs[16][270];

  const int tid = threadIdx.x;
  const int lane = tid & 63, w = tid >> 6, m = lane & 15, quad = lane >> 4;
  const int b = blockIdx.y, n0 = blockIdx.x * 16;
  constexpr size_t BN = (size_t)B_ * N_;

  #pragma unroll
  for (int it = 0; it < 2; ++it) {
    int chunk = tid + it * 256;
    int row = chunk >> 5, col = (chunk & 31) * 8;
    size_t nrow = (size_t)b * N_ + n0 + row;

    float mm0 = ml[nrow], mm1 = ml[BN + nrow];
    float M = fmaxf(mm0, mm1);
    float ws[2];
    ws[0] = ml[2 * BN + nrow] * exp2f(mm0 - M);
    ws[1] = ml[3 * BN + nrow] * exp2f(mm1 - M);
    float inv = 1.f / (ws[0] + ws[1]);
    ws[0] *= inv; ws[1] *= inv;

    uint4 xv = *(const uint4*)(xTh + nrow * C_ + col);
    u32 xq[4] = {xv.x, xv.y, xv.z, xv.w};
    float acc[8];
    #pragma unroll
    for (int j = 0; j < 4; ++j) {
      acc[2 * j]     = bf2f((u16)(xq[j] & 0xffff));
      acc[2 * j + 1] = bf2f((u16)(xq[j] >> 16));
    }
    #pragma unroll
    for (int s = 0; s < 2; ++s) {
      uint4 ovv = *(const uint4*)(Onorm + (s * BN + nrow) * C_ + col);
      u32 oq[4] = {ovv.x, ovv.y, ovv.z, ovv.w};
      #pragma unroll
      for (int j = 0; j < 4; ++j) {
        acc[2 * j]     += ws[s] * bf2f((u16)(oq[j] & 0xffff));
        acc[2 * j + 1] += ws[s] * bf2f((u16)(oq[j] >> 16));
      }
    }
    uint4 pk;
    pk.x = (u32)f2bf(acc[0]) | ((u32)f2bf(acc[1]) << 16);
    pk.y = (u32)f2bf(acc[2]) | ((u32)f2bf(acc[3]) << 16);
    pk.z = (u32)f2bf(acc[4]) | ((u32)f2bf(acc[5]) << 16);
    pk.w = (u32)f2bf(acc[6]) | ((u32)f2bf(acc[7]) << 16);
    *(uint4*)&hs[row][col] = pk;
  }
  __syncthreads();

  f32x4 o[4];
  #pragma unroll
  for (int dt = 0; dt < 4; ++dt) o[dt] = (f32x4){0.f, 0.f, 0.f, 0.f};

  for (int K = 0; K < 8; ++K) {
    const int ko = K * 32 + quad * 8;
    bf16x8 hf = *(const bf16x8*)&hs[m][ko];
    #pragma unroll
    for (int dt = 0; dt < 4; ++dt) {
      bf16x8 whi = *(const bf16x8*)(WoH + (size_t)(64 * w + dt * 16 + m) * C_ + ko);
      bf16x8 wlo = *(const bf16x8*)(WoL + (size_t)(64 * w + dt * 16 + m) * C_ + ko);
      o[dt] = __builtin_amdgcn_mfma_f32_16x16x32_bf16(whi, hf, o[dt], 0, 0, 0);
      o[dt] = __builtin_amdgcn_mfma_f32_16x16x32_bf16(wlo, hf, o[dt], 0, 0, 0);
    }
  }

  #pragma unroll
  for (int dt = 0; dt < 4; ++dt)
    #pragma unroll
    for (int r = 0; r < 4; ++r) {
      int d = 64 * w + dt * 16 + quad * 4 + r;
      out[((size_t)b * C_ + d) * N_ + n0 + m] = o[dt][r] + bo[d];
    }
}

// ---------------------------------------------------------------------------
extern "C" void kernel_launch(void* const* d_in, const int* in_sizes, int n_in,
                              void* d_out, int out_size, void* d_ws, size_t ws_size,
                              hipStream_t stream)
{
  const float* x  = (const float*)d_in[0];
  const float* Wq = (const float*)d_in[1];
  const float* bq = (const float*)d_in[2];
  const float* Wk = (const float*)d_in[3];
  const float* bk = (const float*)d_in[4];
  const float* Wv = (const float*)d_in[5];
  const float* bv = (const float*)d_in[6];
  const float* Wo = (const float*)d_in[7];
  const float* bo = (const float*)d_in[8];

  // workspace. Onorm ALIASES the old xTl slot (xTl no longer exists).
  u16* p = (u16*)d_ws;
  u16* qt  = p;  p += (size_t)B_ * N_ * C8_;   // 1 MB
  u16* kt  = p;  p += (size_t)B_ * N_ * C8_;   // 1 MB
  u16* vb  = p;  p += (size_t)B_ * C_ * N_;    // 8 MB
  u16* xTh = p;  p += (size_t)B_ * N_ * C_;    // 8 MB
  u16* WqH = p;  p += 8192;
  u16* WqL = p;  p += 8192;
  u16* WkH = p;  p += 8192;
  u16* WkL = p;  p += 8192;
  u16* WvH = p;  p += 65536;
  u16* WoH = p;  p += 65536;
  u16* WoL = p;  p += 65536;
  float* ml = (float*)p;  p += (size_t)8 * B_ * N_;  // 4*BN floats (2 m + 2 l)
  u16* Onorm = p;                               // 16.8 MB (2,B,N,C) bf16

  float* out = (float*)d_out;

  prep<<<576, 256, 0, stream>>>(Wq, Wk, Wv, Wo,
      WqH, WqL, WkH, WkL, WvH, WoH, WoL);
  qkv_mfma<<<dim3(N_ / 16, B_), 256, 0, stream>>>(
      x, WqH, WqL, WkH, WkL, WvH, bq, bk, bv, qt, kt, vb, xTh);
  attn_mfma<<<dim3(N_ / 64, 2, B_), 256, 0, stream>>>(qt, kt, vb, Onorm, ml);
  out_mfma<<<dim3(N_ / 16, B_), 256, 0, stream>>>(Onorm, ml, xTh, WoH, WoL, bo, out);
}

// Round 15
// 197.840 us; speedup vs baseline: 1.1234x; 1.1234x over previous
//
#include <hip/hip_runtime.h>

#define DEV __device__ __forceinline__

constexpr int B_  = 4;
constexpr int C_  = 256;
constexpr int C8_ = 32;
constexpr int N_  = 4096;   // 64*64
constexpr float LOG2E = 1.4426950408889634f;

using u16 = unsigned short;
using u32 = unsigned int;

typedef __attribute__((ext_vector_type(8))) short bf16x8;
typedef __attribute__((ext_vector_type(4))) float f32x4;

DEV float bf2f(u16 u) { return __uint_as_float(((u32)u) << 16); }
DEV u16   f2bf(float f) {
  u32 i = __float_as_uint(f);
  i += 0x7fffu + ((i >> 16) & 1u);   // round-to-nearest-even
  return (u16)(i >> 16);
}
// pack two floats to bf16x2 (RTZ) in ONE v_perm_b32
DEV u32 pack_rtz(float a, float b) {
  return __builtin_amdgcn_perm(__float_as_uint(b), __float_as_uint(a), 0x07060302);
}

// LDS-only barrier: cross-wave data is in LDS only -> skip the vmcnt(0) drain
DEV void lds_barrier() {
  asm volatile("s_waitcnt lgkmcnt(0)\n\ts_barrier" ::: "memory");
}

// ---------------------------------------------------------------------------
// prep: WEIGHTS ONLY (x-transpose fused into qkv_mfma, r9).
//   Wq*log2e, Wk -> hi/lo; Wv -> hi; Wo -> hi/lo.   grid 576.
// ---------------------------------------------------------------------------
__global__ __launch_bounds__(256) void prep(
    const float* __restrict__ Wq, const float* __restrict__ Wk,
    const float* __restrict__ Wv, const float* __restrict__ Wo,
    u16* __restrict__ WqH, u16* __restrict__ WqL,
    u16* __restrict__ WkH, u16* __restrict__ WkL,
    u16* __restrict__ WvH,
    u16* __restrict__ WoH, u16* __restrict__ WoL)
{
  const int i = blockIdx.x * 256 + threadIdx.x;
  if (i < 8192) {
    float v = Wq[i] * LOG2E;
    u16 h = f2bf(v); WqH[i] = h; WqL[i] = f2bf(v - bf2f(h));
  } else if (i < 16384) {
    int off = i - 8192;
    float v = Wk[off];
    u16 h = f2bf(v); WkH[off] = h; WkL[off] = f2bf(v - bf2f(h));
  } else if (i < 81920) {
    int off = i - 16384;
    WvH[off] = f2bf(Wv[off]);
  } else {
    int off = i - 81920;
    float v = Wo[off];
    u16 h = f2bf(v); WoH[off] = h; WoL[off] = f2bf(v - bf2f(h));
  }
}

// ---------------------------------------------------------------------------
// q/k/v projections + FUSED x-transpose (r9) + float4 stage-1 (r12).
// Round-15 (= r12 resubmit, session-best 198.0us): r13/r14's 16-pixel tiles
// REGRESSED aux 110->134us — halving the tile keeps the per-block weight-load
// chain identical while halving its MFMA work; 2x blocks x same latency-chain
// = loss.  32-pixel tiles are the measured optimum.
// grid (N/32, B), block 256.
// ---------------------------------------------------------------------------
__global__ __launch_bounds__(256) void qkv_mfma(
    const float* __restrict__ x,
    const u16* __restrict__ WqH, const u16* __restrict__ WqL,
    const u16* __restrict__ WkH, const u16* __restrict__ WkL,
    const u16* __restrict__ WvH,
    const float* __restrict__ bq, const float* __restrict__ bk,
    const float* __restrict__ bv,
    u16* __restrict__ qt, u16* __restrict__ kt, u16* __restrict__ vb,
    u16* __restrict__ xTh)
{
  __shared__ float tf[32][261];            // 261: distinct-bank column writes
  __shared__ __align__(16) u16 xsh[32][270];
  __shared__ __align__(16) u16 xsl[32][270];

  const int tid = threadIdx.x;
  const int lane = tid & 63, w = tid >> 6, m = lane & 15, quad = lane >> 4;
  const int b = blockIdx.y, n0 = blockIdx.x * 32;

  // --- stage 1: x rows -> tf, float4 along n (8 lanes cover one 32-n row)
  {
    const int row = tid >> 3, seg = (tid & 7) * 4;
    #pragma unroll
    for (int it = 0; it < 8; ++it) {
      int c = it * 32 + row;
      float4 v = *(const float4*)&x[((size_t)b * C_ + c) * N_ + n0 + seg];
      tf[seg + 0][c] = v.x;
      tf[seg + 1][c] = v.y;
      tf[seg + 2][c] = v.z;
      tf[seg + 3][c] = v.w;
    }
  }
  __syncthreads();

  // --- stage 2: convert to hi/lo bf16; write LDS tiles + xTh side-output
  {
    const int n = tid >> 3;                          // 0..31
    const int cb = (tid & 7) * 8;                    // bank-spread: c = cb+64*it
    #pragma unroll
    for (int it = 0; it < 4; ++it) {
      int c = cb + it * 64;
      u32 ph[4], pl[4];
      #pragma unroll
      for (int j = 0; j < 4; ++j) {
        float v0 = tf[n][c + 2 * j], v1 = tf[n][c + 2 * j + 1];
        u16 h0 = f2bf(v0), h1 = f2bf(v1);
        ph[j] = (u32)h0 | ((u32)h1 << 16);
        pl[j] = (u32)f2bf(v0 - bf2f(h0)) | ((u32)f2bf(v1 - bf2f(h1)) << 16);
      }
      uint4 hv = make_uint4(ph[0], ph[1], ph[2], ph[3]);
      *(uint4*)&xsh[n][c] = hv;
      *(uint4*)&xsl[n][c] = make_uint4(pl[0], pl[1], pl[2], pl[3]);
      *(uint4*)&xTh[((size_t)b * N_ + n0 + n) * C_ + c] = hv;
    }
  }
  __syncthreads();

  const u16* qkH = (w < 2) ? (WqH + (size_t)(w * 16 + m) * C_)
                           : (WkH + (size_t)((w - 2) * 16 + m) * C_);
  const u16* qkL = (w < 2) ? (WqL + (size_t)(w * 16 + m) * C_)
                           : (WkL + (size_t)((w - 2) * 16 + m) * C_);

  f32x4 ov[4][2], oq[2];
  #pragma unroll
  for (int dt = 0; dt < 4; ++dt)
    #pragma unroll
    for (int nt = 0; nt < 2; ++nt) ov[dt][nt] = (f32x4){0.f, 0.f, 0.f, 0.f};
  #pragma unroll
  for (int nt = 0; nt < 2; ++nt) oq[nt] = (f32x4){0.f, 0.f, 0.f, 0.f};

  for (int K = 0; K < 8; ++K) {
    const int ko = K * 32 + quad * 8;
    bf16x8 xh[2], xl[2];
    #pragma unroll
    for (int nt = 0; nt < 2; ++nt) {
      xh[nt] = *(const bf16x8*)&xsh[nt * 16 + m][ko];
      xl[nt] = *(const bf16x8*)&xsl[nt * 16 + m][ko];
    }
    #pragma unroll
    for (int dt = 0; dt < 4; ++dt) {
      bf16x8 whi = *(const bf16x8*)(WvH + (size_t)(64 * w + dt * 16 + m) * C_ + ko);
      #pragma unroll
      for (int nt = 0; nt < 2; ++nt)
        ov[dt][nt] = __builtin_amdgcn_mfma_f32_16x16x32_bf16(whi, xh[nt], ov[dt][nt], 0, 0, 0);
    }
    {
      bf16x8 bhi = *(const bf16x8*)(qkH + ko);
      bf16x8 blo = *(const bf16x8*)(qkL + ko);
      #pragma unroll
      for (int nt = 0; nt < 2; ++nt) {
        oq[nt] = __builtin_amdgcn_mfma_f32_16x16x32_bf16(xh[nt], bhi, oq[nt], 0, 0, 0);
        oq[nt] = __builtin_amdgcn_mfma_f32_16x16x32_bf16(xl[nt], bhi, oq[nt], 0, 0, 0);
        oq[nt] = __builtin_amdgcn_mfma_f32_16x16x32_bf16(xh[nt], blo, oq[nt], 0, 0, 0);
      }
    }
  }

  #pragma unroll
  for (int dt = 0; dt < 4; ++dt)
    #pragma unroll
    for (int r = 0; r < 4; ++r) {
      int oc = 64 * w + dt * 16 + quad * 4 + r;
      float bias = bv[oc];
      #pragma unroll
      for (int nt = 0; nt < 2; ++nt)
        vb[((size_t)b * C_ + oc) * N_ + n0 + nt * 16 + m] = f2bf(ov[dt][nt][r] + bias);
    }
  {
    u16* qk_out = (w < 2) ? qt : kt;
    int dbase = (w & 1) * 16;
    float bias = (w < 2) ? bq[dbase + m] * LOG2E : bk[dbase + m];
    #pragma unroll
    for (int nt = 0; nt < 2; ++nt)
      #pragma unroll
      for (int r = 0; r < 4; ++r)
        qk_out[((size_t)b * N_ + n0 + nt * 16 + quad * 4 + r) * C8_ + dbase + m] =
            f2bf(oq[nt][r] + bias);
  }
}

// ---------------------------------------------------------------------------
// MFMA flash attention, SPLIT-K=2, TJ=128, exp2 softmax, defer-max.
// (byte-identical to r9/r12: attn ~88us.  Scheduling grafts 0-for-3 here —
// serial schedule + 2-wave TLP is this structure's optimum.)
// grid (N/64, 2, B) linearized; block 256 (4 waves).
// ---------------------------------------------------------------------------
__global__ __launch_bounds__(256) void attn_mfma(
    const u16* __restrict__ qt, const u16* __restrict__ kt,
    const u16* __restrict__ vb,
    u16* __restrict__ Onorm, float* __restrict__ ml)
{
  __shared__ __align__(16) u16  ps[2][64][136];
  __shared__ __align__(16) float als[2][64];
  __shared__ float lfin[64];

  const int tid = threadIdx.x, lane = tid & 63, w = tid >> 6;
  const int m = lane & 15, quad = lane >> 4;

  const int lid = blockIdx.x + gridDim.x * (blockIdx.y + gridDim.y * blockIdx.z);
  const int grp = lid & 7, ksl = grp & 1, b = grp >> 1;
  const int i0 = (lid >> 3) * 64;

  const bf16x8 qfrag =
      *(const bf16x8*)(qt + ((size_t)b * N_ + i0 + w * 16 + m) * C8_ + quad * 8);
  const u16* kbase = kt + (size_t)b * N_ * C8_;
  const u16* vrow  = vb + ((size_t)b * C_ + w * 64 + m) * N_;

  f32x4 o[4][4];
  #pragma unroll
  for (int t = 0; t < 4; ++t)
    #pragma unroll
    for (int ct = 0; ct < 4; ++ct) o[t][ct] = (f32x4){0.f, 0.f, 0.f, 0.f};
  float m_r = -1e30f, l_r = 0.f;

  const int jbeg = ksl * 2048, jend = jbeg + 2048;
  int buf = 0;

  for (int j0 = jbeg; j0 < jend; j0 += 128, buf ^= 1) {
    // --- S, K in two register halves (peak 16 K-regs instead of 32)
    f32x4 s[8];
    bf16x8 kA[4];
    #pragma unroll
    for (int t = 0; t < 4; ++t)
      kA[t] = *(const bf16x8*)(kbase + (size_t)(j0 + t * 16 + m) * C8_ + quad * 8);
    #pragma unroll
    for (int t = 0; t < 4; ++t)
      s[t] = __builtin_amdgcn_mfma_f32_16x16x32_bf16(
          kA[t], qfrag, (f32x4){0.f, 0.f, 0.f, 0.f}, 0, 0, 0);
    // V first half (kk=0,1) issued here: consumed after the barrier
    bf16x8 vB[4][2];
    #pragma unroll
    for (int ct = 0; ct < 4; ++ct)
      #pragma unroll
      for (int kk = 0; kk < 2; ++kk)
        vB[ct][kk] = *(const bf16x8*)(vrow + (size_t)ct * 16 * N_ + j0 + kk * 32 + quad * 8);
    #pragma unroll
    for (int t = 0; t < 4; ++t)
      kA[t] = *(const bf16x8*)(kbase + (size_t)(j0 + (t + 4) * 16 + m) * C8_ + quad * 8);
    #pragma unroll
    for (int t = 0; t < 4; ++t)
      s[t + 4] = __builtin_amdgcn_mfma_f32_16x16x32_bf16(
          kA[t], qfrag, (f32x4){0.f, 0.f, 0.f, 0.f}, 0, 0, 0);

    // --- register online softmax, IN-PLACE on s (log2 domain)
    float mx = -1e30f;
    #pragma unroll
    for (int t = 0; t < 8; ++t)
      #pragma unroll
      for (int r = 0; r < 4; ++r) mx = fmaxf(mx, s[t][r]);
    mx = fmaxf(mx, __shfl_xor(mx, 16));
    mx = fmaxf(mx, __shfl_xor(mx, 32));
    // defer-max: keep stale max while tile max grows <= 8 (P <= 2^8, bf16-safe)
    float mn = (mx - m_r <= 8.f) ? m_r : mx;
    float al = exp2f(m_r - mn);          // == 1.0f exactly when deferred
    m_r = mn;
    float sm = 0.f;
    #pragma unroll
    for (int t = 0; t < 8; ++t)
      #pragma unroll
      for (int r = 0; r < 4; ++r) {
        s[t][r] = exp2f(s[t][r] - mn);
        sm += s[t][r];
      }
    sm += __shfl_xor(sm, 16);
    sm += __shfl_xor(sm, 32);
    l_r = l_r * al + sm;

    #pragma unroll
    for (int t = 0; t < 8; ++t)
      *(uint2*)&ps[buf][w * 16 + m][t * 16 + quad * 4] =
          make_uint2(pack_rtz(s[t][0], s[t][1]), pack_rtz(s[t][2], s[t][3]));
    if (quad == 0) als[buf][w * 16 + m] = al;

    lds_barrier();   // LDS visibility only; V loads stay outstanding

    // --- rescale O (skipped when every row's al == 1, the common deferred case)
    #pragma unroll
    for (int t = 0; t < 4; ++t) {
      float4 alv = *(const float4*)&als[buf][t * 16 + quad * 4];
      int need = (alv.x < 1.f) | (alv.y < 1.f) | (alv.z < 1.f) | (alv.w < 1.f);
      if (__any(need)) {
        #pragma unroll
        for (int ct = 0; ct < 4; ++ct) {
          o[t][ct][0] *= alv.x; o[t][ct][1] *= alv.y;
          o[t][ct][2] *= alv.z; o[t][ct][3] *= alv.w;
        }
      }
    }

    // --- PV kk = 0,1
    #pragma unroll
    for (int kk = 0; kk < 2; ++kk)
      #pragma unroll
      for (int t = 0; t < 4; ++t) {
        bf16x8 pf = *(const bf16x8*)&ps[buf][t * 16 + m][kk * 32 + quad * 8];
        #pragma unroll
        for (int ct = 0; ct < 4; ++ct)
          o[t][ct] = __builtin_amdgcn_mfma_f32_16x16x32_bf16(pf, vB[ct][kk], o[t][ct], 0, 0, 0);
      }

    // pin: reload of V (kk=2,3) must NOT be hoisted above PV kk=0,1
    __builtin_amdgcn_sched_barrier(0);

    #pragma unroll
    for (int ct = 0; ct < 4; ++ct)
      #pragma unroll
      for (int kk = 0; kk < 2; ++kk)
        vB[ct][kk] = *(const bf16x8*)(vrow + (size_t)ct * 16 * N_ + j0 + (kk + 2) * 32 + quad * 8);

    // --- PV kk = 2,3
    #pragma unroll
    for (int kk = 0; kk < 2; ++kk)
      #pragma unroll
      for (int t = 0; t < 4; ++t) {
        bf16x8 pf = *(const bf16x8*)&ps[buf][t * 16 + m][(kk + 2) * 32 + quad * 8];
        #pragma unroll
        for (int ct = 0; ct < 4; ++ct)
          o[t][ct] = __builtin_amdgcn_mfma_f32_16x16x32_bf16(pf, vB[ct][kk], o[t][ct], 0, 0, 0);
      }
  }

  // share 1/l across waves (O rows span all 64 block queries)
  if (quad == 0) lfin[w * 16 + m] = 1.f / l_r;
  lds_barrier();

  u16* Ob = Onorm + (((size_t)ksl * B_ + b) * N_ + i0) * C_ + w * 64;
  #pragma unroll
  for (int t = 0; t < 4; ++t) {
    float4 lv = *(const float4*)&lfin[t * 16 + quad * 4];
    float linv[4] = {lv.x, lv.y, lv.z, lv.w};
    #pragma unroll
    for (int ct = 0; ct < 4; ++ct)
      #pragma unroll
      for (int r = 0; r < 4; ++r)
        Ob[(size_t)(t * 16 + quad * 4 + r) * C_ + ct * 16 + m] = f2bf(o[t][ct][r] * linv[r]);
  }

  if (quad == 0) {
    size_t mli = ((size_t)ksl * B_ + b) * N_ + i0 + w * 16 + m;
    ml[mli] = m_r;                                   // m_s at s*BN
    ml[(size_t)2 * B_ * N_ + mli] = l_r;             // l_s at (2+s)*BN
  }
}

// ---------------------------------------------------------------------------
// Fused split-K combine (2 splits) + residual + final 1x1 conv.
// grid (N/32, B), block 256.  (r8 form — 32-pixel tiles, measured optimum)
// ---------------------------------------------------------------------------
__global__ __launch_bounds__(256) void out_mfma(
    const u16* __restrict__ Onorm, const float* __restrict__ ml,
    const u16* __restrict__ xTh,
    const u16* __restrict__ WoH, const u16* __restrict__ WoL,
    const float* __restrict__ bo, float* __restrict__ out)
{
  __shared__ __align__(16) u16 hs[32][270];

  const int tid = threadIdx.x;
  const int lane = tid & 63, w = tid >> 6, m = lane & 15, quad = lane >> 4;
  const int b = blockIdx.y, n0 = blockIdx.x * 32;
  constexpr size_t BN = (size_t)B_ * N_;

  #pragma unroll
  for (int it = 0; it < 4; ++it) {
    int chunk = tid + it * 256;
    int row = chunk >> 5, col = (chunk & 31) * 8;
    size_t nrow = (size_t)b * N_ + n0 + row;

    float mm0 = ml[nrow], mm1 = ml[BN + nrow];
    float M = fmaxf(mm0, mm1);
    float ws[2];
    ws[0] = ml[2 * BN + nrow] * exp2f(mm0 - M);
    ws[1] = ml[3 * BN + nrow] * exp2f(mm1 - M);
    float inv = 1.f / (ws[0] + ws[1]);
    ws[0] *= inv; ws[1] *= inv;

    uint4 xv = *(const uint4*)(xTh + nrow * C_ + col);
    u32 xq[4] = {xv.x, xv.y, xv.z, xv.w};
    float acc[8];
    #pragma unroll
    for (int j = 0; j < 4; ++j) {
      acc[2 * j]     = bf2f((u16)(xq[j] & 0xffff));
      acc[2 * j + 1] = bf2f((u16)(xq[j] >> 16));
    }
    #pragma unroll
    for (int s = 0; s < 2; ++s) {
      uint4 ovv = *(const uint4*)(Onorm + (s * BN + nrow) * C_ + col);
      u32 oq[4] = {ovv.x, ovv.y, ovv.z, ovv.w};
      #pragma unroll
      for (int j = 0; j < 4; ++j) {
        acc[2 * j]     += ws[s] * bf2f((u16)(oq[j] & 0xffff));
        acc[2 * j + 1] += ws[s] * bf2f((u16)(oq[j] >> 16));
      }
    }
    uint4 pk;
    pk.x = (u32)f2bf(acc[0]) | ((u32)f2bf(acc[1]) << 16);
    pk.y = (u32)f2bf(acc[2]) | ((u32)f2bf(acc[3]) << 16);
    pk.z = (u32)f2bf(acc[4]) | ((u32)f2bf(acc[5]) << 16);
    pk.w = (u32)f2bf(acc[6]) | ((u32)f2bf(acc[7]) << 16);
    *(uint4*)&hs[row][col] = pk;
  }
  __syncthreads();

  f32x4 o[4][2];
  #pragma unroll
  for (int dt = 0; dt < 4; ++dt)
    #pragma unroll
    for (int nt = 0; nt < 2; ++nt) o[dt][nt] = (f32x4){0.f, 0.f, 0.f, 0.f};

  for (int K = 0; K < 8; ++K) {
    const int ko = K * 32 + quad * 8;
    bf16x8 hf[2];
    #pragma unroll
    for (int nt = 0; nt < 2; ++nt) hf[nt] = *(const bf16x8*)&hs[nt * 16 + m][ko];
    #pragma unroll
    for (int dt = 0; dt < 4; ++dt) {
      bf16x8 whi = *(const bf16x8*)(WoH + (size_t)(64 * w + dt * 16 + m) * C_ + ko);
      bf16x8 wlo = *(const bf16x8*)(WoL + (size_t)(64 * w + dt * 16 + m) * C_ + ko);
      #pragma unroll
      for (int nt = 0; nt < 2; ++nt) {
        o[dt][nt] = __builtin_amdgcn_mfma_f32_16x16x32_bf16(whi, hf[nt], o[dt][nt], 0, 0, 0);
        o[dt][nt] = __builtin_amdgcn_mfma_f32_16x16x32_bf16(wlo, hf[nt], o[dt][nt], 0, 0, 0);
      }
    }
  }

  #pragma unroll
  for (int dt = 0; dt < 4; ++dt)
    #pragma unroll
    for (int r = 0; r < 4; ++r) {
      int d = 64 * w + dt * 16 + quad * 4 + r;
      float bias = bo[d];
      #pragma unroll
      for (int nt = 0; nt < 2; ++nt)
        out[((size_t)b * C_ + d) * N_ + n0 + nt * 16 + m] = o[dt][nt][r] + bias;
    }
}

// ---------------------------------------------------------------------------
extern "C" void kernel_launch(void* const* d_in, const int* in_sizes, int n_in,
                              void* d_out, int out_size, void* d_ws, size_t ws_size,
                              hipStream_t stream)
{
  const float* x  = (const float*)d_in[0];
  const float* Wq = (const float*)d_in[1];
  const float* bq = (const float*)d_in[2];
  const float* Wk = (const float*)d_in[3];
  const float* bk = (const float*)d_in[4];
  const float* Wv = (const float*)d_in[5];
  const float* bv = (const float*)d_in[6];
  const float* Wo = (const float*)d_in[7];
  const float* bo = (const float*)d_in[8];

  // workspace. Onorm ALIASES the old xTl slot (xTl no longer exists).
  u16* p = (u16*)d_ws;
  u16* qt  = p;  p += (size_t)B_ * N_ * C8_;   // 1 MB
  u16* kt  = p;  p += (size_t)B_ * N_ * C8_;   // 1 MB
  u16* vb  = p;  p += (size_t)B_ * C_ * N_;    // 8 MB
  u16* xTh = p;  p += (size_t)B_ * N_ * C_;    // 8 MB
  u16* WqH = p;  p += 8192;
  u16* WqL = p;  p += 8192;
  u16* WkH = p;  p += 8192;
  u16* WkL = p;  p += 8192;
  u16* WvH = p;  p += 65536;
  u16* WoH = p;  p += 65536;
  u16* WoL = p;  p += 65536;
  float* ml = (float*)p;  p += (size_t)8 * B_ * N_;  // 4*BN floats (2 m + 2 l)
  u16* Onorm = p;                               // 16.8 MB (2,B,N,C) bf16

  float* out = (float*)d_out;

  prep<<<576, 256, 0, stream>>>(Wq, Wk, Wv, Wo,
      WqH, WqL, WkH, WkL, WvH, WoH, WoL);
  qkv_mfma<<<dim3(N_ / 32, B_), 256, 0, stream>>>(
      x, WqH, WqL, WkH, WkL, WvH, bq, bk, bv, qt, kt, vb, xTh);
  attn_mfma<<<dim3(N_ / 64, 2, B_), 256, 0, stream>>>(qt, kt, vb, Onorm, ml);
  out_mfma<<<dim3(N_ / 32, B_), 256, 0, stream>>>(Onorm, ml, xTh, WoH, WoL, bo, out);
}